// Round 1
// baseline (2798.720 us; speedup 1.0000x reference)
//
#include <hip/hip_runtime.h>
#include <cstdint>

#define VOC   32768
#define DIM   512
#define TOPK  64
#define BATCH 4096

// ---------------------------------------------------------------------------
// Tiled fp32 GEMM.  C(MxN) = A(MxK) * B (+bias)
//   BT=false: B is KxN row-major (NN)
//   BT=true : B is NxK row-major (NT, C = A*B^T)
// Tile: 128(M) x 64(N), K-step 16, 256 threads, 8x4 microtile/thread.
// M % 128 == 0, N % 64 == 0, K % 16 == 0 (all shapes here comply).
// ---------------------------------------------------------------------------
template <bool BT>
__global__ __launch_bounds__(256)
void gemm_kernel(const float* __restrict__ A, const float* __restrict__ B,
                 const float* __restrict__ bias, float* __restrict__ C,
                 int M, int N, int K)
{
    const int BM = 128, BN = 64, KS = 16;
    __shared__ float As[KS][BM + 4];   // stride 132 floats = 528B (16B-aligned)
    __shared__ float Bs[KS][BN];

    const int tid = threadIdx.x;
    const int m0 = blockIdx.y * BM;
    const int n0 = blockIdx.x * BN;
    const int ty = tid >> 4;           // 0..15 -> rows ty*8..ty*8+7
    const int tx = tid & 15;           // 0..15 -> cols tx*4..tx*4+3

    float acc[8][4];
#pragma unroll
    for (int i = 0; i < 8; i++)
#pragma unroll
        for (int j = 0; j < 4; j++) acc[i][j] = 0.f;

    for (int kt = 0; kt < K; kt += KS) {
        // stage A tile (128 x 16), transposed into As[k][m]
#pragma unroll
        for (int s = 0; s < 2; s++) {
            int c = tid + s * 256;          // 0..511
            int row = c >> 2;               // 0..127
            int kq  = c & 3;                // 0..3 (float4 chunk)
            const float4 av = *(const float4*)(A + (size_t)(m0 + row) * K + kt + kq * 4);
            As[kq * 4 + 0][row] = av.x;
            As[kq * 4 + 1][row] = av.y;
            As[kq * 4 + 2][row] = av.z;
            As[kq * 4 + 3][row] = av.w;
        }
        if (!BT) {
            // B tile: 16(k) x 64(n), direct
            int krow = tid >> 4;            // 0..15
            int nq   = tid & 15;            // 0..15
            const float4 bv = *(const float4*)(B + (size_t)(kt + krow) * N + n0 + nq * 4);
            *(float4*)&Bs[krow][nq * 4] = bv;
        } else {
            // B tile: 64(n) x 16(k), transpose into Bs[k][n]
            int nrow = tid >> 2;            // 0..63
            int kq   = tid & 3;             // 0..3
            const float4 bv = *(const float4*)(B + (size_t)(n0 + nrow) * K + kt + kq * 4);
            Bs[kq * 4 + 0][nrow] = bv.x;
            Bs[kq * 4 + 1][nrow] = bv.y;
            Bs[kq * 4 + 2][nrow] = bv.z;
            Bs[kq * 4 + 3][nrow] = bv.w;
        }
        __syncthreads();

#pragma unroll
        for (int kk = 0; kk < KS; kk++) {
            float4 a0 = *(const float4*)&As[kk][ty * 8];
            float4 a1 = *(const float4*)&As[kk][ty * 8 + 4];
            float4 b  = *(const float4*)&Bs[kk][tx * 4];
            float av[8] = {a0.x, a0.y, a0.z, a0.w, a1.x, a1.y, a1.z, a1.w};
            float bv[4] = {b.x, b.y, b.z, b.w};
#pragma unroll
            for (int i = 0; i < 8; i++)
#pragma unroll
                for (int j = 0; j < 4; j++)
                    acc[i][j] += av[i] * bv[j];
        }
        __syncthreads();
    }

    float4 bb = make_float4(0.f, 0.f, 0.f, 0.f);
    if (bias) bb = *(const float4*)(bias + n0 + tx * 4);
#pragma unroll
    for (int i = 0; i < 8; i++) {
        float4 o;
        o.x = acc[i][0] + bb.x;
        o.y = acc[i][1] + bb.y;
        o.z = acc[i][2] + bb.z;
        o.w = acc[i][3] + bb.w;
        *(float4*)(C + (size_t)(m0 + ty * 8 + i) * N + n0 + tx * 4) = o;
    }
}

// ---------------------------------------------------------------------------
// Per-row top-64 threshold + softmax + out = attn @ v.
// One workgroup (256 threads) per batch row.
// Exact selection: 13-bit sortable-float-key histogram locates the boundary
// bin; all candidates (bin >= boundary) are collected (expected ~80, cap 256)
// and bitonic-sorted to get the exact 64th-largest value. All entries
// >= thresh are kept (matches reference tie semantics); softmax over them.
// ---------------------------------------------------------------------------
__global__ __launch_bounds__(256)
void select_kernel(const float* __restrict__ dots, const float* __restrict__ v,
                   float* __restrict__ out, int rowOffset)
{
    __shared__ unsigned int hist[8192];
    __shared__ unsigned long long keys[256];
    __shared__ float wArr[256];
    __shared__ float redf[256];
    __shared__ unsigned int redu[256];
    __shared__ unsigned int s_cnt;
    __shared__ unsigned int s_bbin;
    __shared__ float s_max;

    const int tid = threadIdx.x;
    const float* row = dots + (size_t)blockIdx.x * VOC;

    for (int i = tid; i < 8192; i += 256) hist[i] = 0;
    if (tid == 0) s_cnt = 0;
    __syncthreads();

    // ---- pass 0: histogram of top-13 bits of sortable key, and row max ----
    float lmax = -3.4e38f;
    for (int i = tid; i < VOC; i += 256) {
        float vv = row[i];
        lmax = fmaxf(lmax, vv);
        unsigned int b = __float_as_uint(vv);
        unsigned int key = (b & 0x80000000u) ? ~b : (b | 0x80000000u);
        atomicAdd(&hist[key >> 19], 1u);
    }
    redf[tid] = lmax;
    __syncthreads();
    for (int s = 128; s > 0; s >>= 1) {
        if (tid < s) redf[tid] = fmaxf(redf[tid], redf[tid + s]);
        __syncthreads();
    }
    if (tid == 0) s_max = redf[0];

    // ---- locate boundary bin (descending cumulative reaches TOPK) ----
    unsigned int segsum = 0;
    for (int b = 0; b < 32; b++) segsum += hist[tid * 32 + b];
    redu[tid] = segsum;
    __syncthreads();
    if (tid == 0) {
        unsigned int cum = 0;
        int seg = 0;
        for (int s = 255; s >= 0; s--) {
            if (cum + redu[s] >= TOPK) { seg = s; break; }
            cum += redu[s];
        }
        unsigned int bbin = (unsigned int)(seg * 32);
        for (int b = seg * 32 + 31; b >= seg * 32; b--) {
            if (cum + hist[b] >= TOPK) { bbin = (unsigned int)b; break; }
            cum += hist[b];
        }
        s_bbin = bbin;
    }
    __syncthreads();

    // ---- pass 1: collect all candidates with bin >= boundary ----
    const unsigned int bbin = s_bbin;
    for (int i = tid; i < VOC; i += 256) {
        float vv = row[i];
        unsigned int b = __float_as_uint(vv);
        unsigned int key = (b & 0x80000000u) ? ~b : (b | 0x80000000u);
        if ((key >> 19) >= bbin) {
            unsigned int p = atomicAdd(&s_cnt, 1u);
            if (p < 256)
                keys[p] = ((unsigned long long)(~key) << 32) | (unsigned int)i;
        }
    }
    __syncthreads();
    unsigned int cnt = s_cnt;
    if (cnt > 256) cnt = 256;
    if (tid >= (int)cnt) keys[tid] = ~0ULL;   // pad: sorts to the end
    __syncthreads();

    // ---- bitonic sort 256 u64 ascending (= descending by value) ----
    for (int k = 2; k <= 256; k <<= 1) {
        for (int j = k >> 1; j > 0; j >>= 1) {
            int ixj = tid ^ j;
            if (ixj > tid) {
                bool up = ((tid & k) == 0);
                unsigned long long a = keys[tid], b2 = keys[ixj];
                if (up ? (a > b2) : (a < b2)) { keys[tid] = b2; keys[ixj] = a; }
            }
            __syncthreads();
        }
    }

    // ---- threshold (64th largest), weights, Z, selCount ----
    const unsigned int threshInv = (unsigned int)(keys[TOPK - 1] >> 32);
    unsigned long long mine = keys[tid];
    unsigned int hi = (unsigned int)(mine >> 32);
    bool sel = (hi <= threshInv);             // value >= thresh
    unsigned int skey = ~hi;
    unsigned int fbits = (skey & 0x80000000u) ? (skey & 0x7FFFFFFFu) : ~skey;
    float val = __uint_as_float(fbits);
    float w = sel ? expf(val - s_max) : 0.f;
    wArr[tid] = w;
    redf[tid] = w;
    redu[tid] = sel ? 1u : 0u;
    __syncthreads();
    for (int s = 128; s > 0; s >>= 1) {
        if (tid < s) {
            redf[tid] += redf[tid + s];
            redu[tid] += redu[tid + s];
        }
        __syncthreads();
    }
    const float invZ = 1.0f / redf[0];
    const int selCount = (int)redu[0];        // selected entries are a prefix

    // ---- out[row] = (1/Z) * sum_i w_i * v[idx_i, :] ----
    for (int d = tid; d < DIM; d += 256) {
        float acc = 0.f;
        for (int i = 0; i < selCount; i++) {
            unsigned int idx = (unsigned int)(keys[i] & 0xFFFFFFFFu);
            acc += wArr[i] * v[(size_t)idx * DIM + d];
        }
        out[(size_t)(rowOffset + blockIdx.x) * DIM + d] = acc * invZ;
    }
}

// ---------------------------------------------------------------------------
extern "C" void kernel_launch(void* const* d_in, const int* in_sizes, int n_in,
                              void* d_out, int out_size, void* d_ws, size_t ws_size,
                              hipStream_t stream)
{
    const float* x        = (const float*)d_in[0];
    const float* codebook = (const float*)d_in[1];
    const float* Wq       = (const float*)d_in[2];
    const float* bq       = (const float*)d_in[3];
    const float* Wk       = (const float*)d_in[4];
    // d_in[5] = bk: per-row-constant shift in dots -> invariant under top-k
    // and softmax; intentionally unused.
    const float* Wv       = (const float*)d_in[6];
    const float* bv       = (const float*)d_in[7];
    float* out = (float*)d_out;

    float* q    = (float*)d_ws;                  // 4096 x 512
    float* q2   = q  + (size_t)BATCH * DIM;      // 4096 x 512
    float* v    = q2 + (size_t)BATCH * DIM;      // 32768 x 512
    float* dots = v  + (size_t)VOC * DIM;        // chunk x 32768

    const size_t base = ((size_t)BATCH * DIM * 2 + (size_t)VOC * DIM) * sizeof(float);
    size_t rem = (ws_size > base) ? (ws_size - base) : 0;
    int chunk = (int)(rem / ((size_t)VOC * sizeof(float)));
    if (chunk > BATCH) chunk = BATCH;
    chunk = (chunk / 128) * 128;
    if (chunk < 128) chunk = 128;

    dim3 blk(256);

    // q = x @ Wq + bq
    gemm_kernel<false><<<dim3(DIM / 64, BATCH / 128), blk, 0, stream>>>(
        x, Wq, bq, q, BATCH, DIM, DIM);
    // q2 = q @ Wk^T   (folds k-projection into q; bk dropped — see above)
    gemm_kernel<true><<<dim3(DIM / 64, BATCH / 128), blk, 0, stream>>>(
        q, Wk, nullptr, q2, BATCH, DIM, DIM);
    // v = codebook @ Wv + bv
    gemm_kernel<false><<<dim3(DIM / 64, VOC / 128), blk, 0, stream>>>(
        codebook, Wv, bv, v, VOC, DIM, DIM);

    for (int r0 = 0; r0 < BATCH; r0 += chunk) {
        int rows = BATCH - r0;
        if (rows > chunk) rows = chunk;
        // dots[chunk] = q2[r0:r0+rows] @ codebook^T
        gemm_kernel<true><<<dim3(VOC / 64, rows / 128), blk, 0, stream>>>(
            q2 + (size_t)r0 * DIM, codebook, nullptr, dots, rows, VOC, DIM);
        // top-64 threshold + softmax + attn @ v
        select_kernel<<<dim3(rows), blk, 0, stream>>>(dots, v, out, r0);
    }
}

// Round 3
// 1476.058 us; speedup vs baseline: 1.8961x; 1.8961x over previous
//
#include <hip/hip_runtime.h>
#include <cstdint>

#define VOC   32768
#define DIM   512
#define TOPK  64
#define BATCH 4096

typedef unsigned short u16;
typedef __attribute__((ext_vector_type(8))) short bf16x8;
typedef __attribute__((ext_vector_type(4))) float f32x4;

// ---- bf16 helpers (RNE) ----------------------------------------------------
__device__ __forceinline__ u16 f2bf(float f) {
    unsigned u = __float_as_uint(f);
    unsigned r = (u + 0x7FFFu + ((u >> 16) & 1u)) >> 16;
    return (u16)r;
}
__device__ __forceinline__ float bf2f(u16 h) {
    unsigned u = ((unsigned)h) << 16;
    return __uint_as_float(u);
}

// ---- async global->LDS 16B -------------------------------------------------
__device__ __forceinline__ void async16(const void* g, void* l) {
    __builtin_amdgcn_global_load_lds(
        (const __attribute__((address_space(1))) void*)g,
        (__attribute__((address_space(3))) void*)l, 16, 0, 0);
}

// ---------------------------------------------------------------------------
// fp32 tiled GEMM (round-1, known good) + optional per-k-tile fp64 flush.
//   BT=false: C = A(MxK) * B(KxN) (+bias) ;  BT=true: C = A * B^T, B is NxK
// Tile 128x64, KS=16, 256 thr, 8x4 microtile. M%128==0, N%64==0, K%16==0.
// ---------------------------------------------------------------------------
template <bool BT, bool F64ACC>
__global__ __launch_bounds__(256)
void gemm_kernel(const float* __restrict__ A, const float* __restrict__ B,
                 const float* __restrict__ bias, float* __restrict__ C,
                 int M, int N, int K)
{
    const int BM = 128, BN = 64, KS = 16;
    __shared__ float As[KS][BM + 4];
    __shared__ float Bs[KS][BN];

    const int tid = threadIdx.x;
    const int m0 = blockIdx.y * BM;
    const int n0 = blockIdx.x * BN;
    const int ty = tid >> 4;
    const int tx = tid & 15;

    float acc[8][4];
    double acc64[8][4];
#pragma unroll
    for (int i = 0; i < 8; i++)
#pragma unroll
        for (int j = 0; j < 4; j++) { acc[i][j] = 0.f; if (F64ACC) acc64[i][j] = 0.0; }

    for (int kt = 0; kt < K; kt += KS) {
#pragma unroll
        for (int s = 0; s < 2; s++) {
            int c = tid + s * 256;
            int row = c >> 2;
            int kq  = c & 3;
            const float4 av = *(const float4*)(A + (size_t)(m0 + row) * K + kt + kq * 4);
            As[kq * 4 + 0][row] = av.x;
            As[kq * 4 + 1][row] = av.y;
            As[kq * 4 + 2][row] = av.z;
            As[kq * 4 + 3][row] = av.w;
        }
        if (!BT) {
            int krow = tid >> 4;
            int nq   = tid & 15;
            const float4 bv = *(const float4*)(B + (size_t)(kt + krow) * N + n0 + nq * 4);
            *(float4*)&Bs[krow][nq * 4] = bv;
        } else {
            int nrow = tid >> 2;
            int kq   = tid & 3;
            const float4 bv = *(const float4*)(B + (size_t)(n0 + nrow) * K + kt + kq * 4);
            Bs[kq * 4 + 0][nrow] = bv.x;
            Bs[kq * 4 + 1][nrow] = bv.y;
            Bs[kq * 4 + 2][nrow] = bv.z;
            Bs[kq * 4 + 3][nrow] = bv.w;
        }
        __syncthreads();

#pragma unroll
        for (int kk = 0; kk < KS; kk++) {
            float4 a0 = *(const float4*)&As[kk][ty * 8];
            float4 a1 = *(const float4*)&As[kk][ty * 8 + 4];
            float4 b  = *(const float4*)&Bs[kk][tx * 4];
            float av[8] = {a0.x, a0.y, a0.z, a0.w, a1.x, a1.y, a1.z, a1.w};
            float bv[4] = {b.x, b.y, b.z, b.w};
#pragma unroll
            for (int i = 0; i < 8; i++)
#pragma unroll
                for (int j = 0; j < 4; j++)
                    acc[i][j] += av[i] * bv[j];
        }
        __syncthreads();
        if (F64ACC) {
#pragma unroll
            for (int i = 0; i < 8; i++)
#pragma unroll
                for (int j = 0; j < 4; j++) { acc64[i][j] += (double)acc[i][j]; acc[i][j] = 0.f; }
        }
    }

    float4 bb = make_float4(0.f, 0.f, 0.f, 0.f);
    if (bias) bb = *(const float4*)(bias + n0 + tx * 4);
#pragma unroll
    for (int i = 0; i < 8; i++) {
        float4 o;
        float r0 = F64ACC ? (float)acc64[i][0] : acc[i][0];
        float r1 = F64ACC ? (float)acc64[i][1] : acc[i][1];
        float r2 = F64ACC ? (float)acc64[i][2] : acc[i][2];
        float r3 = F64ACC ? (float)acc64[i][3] : acc[i][3];
        o.x = r0 + bb.x; o.y = r1 + bb.y; o.z = r2 + bb.z; o.w = r3 + bb.w;
        *(float4*)(C + (size_t)(m0 + ty * 8 + i) * N + n0 + tx * 4) = o;
    }
}

// ---------------------------------------------------------------------------
// bqk[e] = sum_d bq[d] * Wk[e][d]
// ---------------------------------------------------------------------------
__global__ void bias_fold(const float* __restrict__ bq, const float* __restrict__ Wk,
                          float* __restrict__ bqk)
{
    int j = blockIdx.x * 256 + threadIdx.x;
    if (j >= DIM) return;
    double s = 0.0;
    const float* wr = Wk + (size_t)j * DIM;
    for (int d = 0; d < DIM; d++) s += (double)bq[d] * (double)wr[d];
    bqk[j] = (float)s;
}

// ---------------------------------------------------------------------------
// Pack fp32 [R x 512] (k contiguous per row) -> MFMA operand layout
//   pk[ks][ch][R][8] bf16,  global k = ks*32 + ch*8 + j.  Optional lo part.
// ---------------------------------------------------------------------------
__global__ __launch_bounds__(256)
void pack_rows(const float* __restrict__ src, u16* __restrict__ hi,
               u16* __restrict__ lo, int R, int log2R)
{
    int idx = blockIdx.x * 256 + threadIdx.x;      // R*64 total
    int c8  = idx >> log2R;
    int row = idx & (R - 1);
    const float* sp = src + (size_t)row * DIM + c8 * 8;
    float xv[8];
    *(float4*)&xv[0] = *(const float4*)sp;
    *(float4*)&xv[4] = *(const float4*)(sp + 4);
    int ks = c8 >> 2, ch = c8 & 3;
    size_t ob = ((size_t)(ks * 4 + ch) * R + row) * 8;
    u16 h[8], l[8];
#pragma unroll
    for (int j = 0; j < 8; j++) {
        h[j] = f2bf(xv[j]);
        l[j] = f2bf(xv[j] - bf2f(h[j]));
    }
    *(uint4*)(hi + ob) = *(const uint4*)h;
    if (lo) *(uint4*)(lo + ob) = *(const uint4*)l;
}

// ---------------------------------------------------------------------------
// Pack Wv (512x512, B-operand: B[k][n]) -> pk[ks][ch][512(n)][8(k)]
// ---------------------------------------------------------------------------
__global__ __launch_bounds__(256)
void pack_bT(const float* __restrict__ W, u16* __restrict__ hi, u16* __restrict__ lo)
{
    int idx = blockIdx.x * 256 + threadIdx.x;      // 512*64 total
    int n  = idx & (DIM - 1);
    int c8 = idx >> 9;
    int ks = c8 >> 2, ch = c8 & 3;
    size_t ob = ((size_t)(ks * 4 + ch) * DIM + n) * 8;
    u16 h[8], l[8];
#pragma unroll
    for (int j = 0; j < 8; j++) {
        float x = W[(size_t)(c8 * 8 + j) * DIM + n];
        h[j] = f2bf(x);
        l[j] = f2bf(x - bf2f(h[j]));
    }
    *(uint4*)(hi + ob) = *(const uint4*)h;
    if (lo) *(uint4*)(lo + ob) = *(const uint4*)l;
}

// ---------------------------------------------------------------------------
// MFMA GEMM: C[m][n] = sum_k A[mBase+m][k]*B[n][k], operands packed
// [ks][ch][R][8] (A rows stride Mpack, B rows stride N). C is chunk-local,
// row stride N. NPROD=1: hi*hi.  NPROD=3: ah*bh + ah*bl + al*bh.
// 128x128 tile, 4 waves (2x2 of 64x64), 16x16x32 bf16 MFMA,
// global_load_lds 16B staging.
// ---------------------------------------------------------------------------
template <int NPROD, bool OUT_BF16>
__global__ __launch_bounds__(256, 2)
void mfma_gemm(const u16* __restrict__ Ah, const u16* __restrict__ Al,
               const u16* __restrict__ Bh, const u16* __restrict__ Bl,
               const float* __restrict__ bias, void* __restrict__ Cout,
               int mBase, int Mpack, int N)
{
    constexpr int NARR = (NPROD == 3) ? 4 : 2;
    __shared__ u16 lds[NARR * 4096];

    const int tid  = threadIdx.x;
    const int lane = tid & 63;
    const int wave = tid >> 6;
    const int wm = wave >> 1, wn = wave & 1;
    const int m0 = blockIdx.y * 128, n0 = blockIdx.x * 128;
    const int lr = lane & 15;
    const int q  = lane >> 4;

    f32x4 acc[4][4] = {};
    const u16* garr[4] = {Ah, Bh, Al, Bl};

    for (int ks = 0; ks < 16; ks++) {
        if (NPROD == 3) {
            const int a = wave;                              // one array per wave
            const u16* src = garr[a];
            const bool isA = (a == 0 || a == 2);
            const int rb = isA ? (mBase + m0) : n0;
            const int R  = isA ? Mpack : N;
#pragma unroll
            for (int i = 0; i < 8; i++) {
                const u16* gp = src + ((size_t)(ks * 4 + (i >> 1)) * R + rb + (i & 1) * 64 + lane) * 8;
                u16* lp = &lds[a * 4096 + i * 512 + lane * 8];
                async16(gp, lp);
            }
        } else {
            const int a = wave >> 1;                         // wave pair per array
            const u16* src = garr[a];
            const bool isA = (a == 0);
            const int rb = isA ? (mBase + m0) : n0;
            const int R  = isA ? Mpack : N;
#pragma unroll
            for (int s = 0; s < 4; s++) {
                int i = (wave & 1) * 4 + s;
                const u16* gp = src + ((size_t)(ks * 4 + (i >> 1)) * R + rb + (i & 1) * 64 + lane) * 8;
                u16* lp = &lds[a * 4096 + i * 512 + lane * 8];
                async16(gp, lp);
            }
        }
        __syncthreads();

        bf16x8 ah[4], al[4];
#pragma unroll
        for (int mt = 0; mt < 4; mt++) {
            int row = wm * 64 + mt * 16 + lr;
            ah[mt] = *(const bf16x8*)&lds[0 * 4096 + q * 1024 + row * 8];
            if (NPROD == 3) al[mt] = *(const bf16x8*)&lds[2 * 4096 + q * 1024 + row * 8];
        }
#pragma unroll
        for (int nt = 0; nt < 4; nt++) {
            int col = wn * 64 + nt * 16 + lr;
            bf16x8 bh = *(const bf16x8*)&lds[1 * 4096 + q * 1024 + col * 8];
            bf16x8 bl;
            if (NPROD == 3) bl = *(const bf16x8*)&lds[3 * 4096 + q * 1024 + col * 8];
#pragma unroll
            for (int mt = 0; mt < 4; mt++) {
                acc[mt][nt] = __builtin_amdgcn_mfma_f32_16x16x32_bf16(ah[mt], bh, acc[mt][nt], 0, 0, 0);
                if (NPROD == 3) {
                    acc[mt][nt] = __builtin_amdgcn_mfma_f32_16x16x32_bf16(ah[mt], bl, acc[mt][nt], 0, 0, 0);
                    acc[mt][nt] = __builtin_amdgcn_mfma_f32_16x16x32_bf16(al[mt], bh, acc[mt][nt], 0, 0, 0);
                }
            }
        }
        __syncthreads();
    }

#pragma unroll
    for (int mt = 0; mt < 4; mt++) {
#pragma unroll
        for (int nt = 0; nt < 4; nt++) {
            int col = n0 + wn * 64 + nt * 16 + lr;
            float bb = bias ? bias[col] : 0.f;
#pragma unroll
            for (int r = 0; r < 4; r++) {
                int rowg = m0 + wm * 64 + mt * 16 + q * 4 + r;   // chunk-local
                float val = acc[mt][nt][r] + bb;
                if (OUT_BF16)
                    ((u16*)Cout)[(size_t)rowg * N + col] = f2bf(val);
                else
                    ((float*)Cout)[(size_t)rowg * N + col] = val;
            }
        }
    }
}

// ---------------------------------------------------------------------------
// Select: per row — histogram of bf16 approx dots -> candidate set (bins >=
// boundary-1, margin >> bf16 GEMM error) -> EXACT fp64 recompute of candidate
// dots -> bitonic rank -> exact 64th threshold (ties kept) -> softmax ->
// out = attn @ v.  dots is chunk-local; q2/out indexed by rowOff+blockIdx.x.
// ---------------------------------------------------------------------------
__global__ __launch_bounds__(256)
void select2(const u16* __restrict__ dots, const float* __restrict__ q2,
             const float* __restrict__ codebook, const float* __restrict__ v,
             float* __restrict__ out, int rowOff)
{
    __shared__ unsigned int hist[8192];
    __shared__ float q2s[DIM];
    __shared__ unsigned long long keys[256];
    __shared__ int candIdx[256];
    __shared__ float wArr[256];
    __shared__ float redf[256];
    __shared__ unsigned int redu[256];
    __shared__ unsigned int s_cnt;
    __shared__ unsigned int s_bstart;

    const int tid = threadIdx.x;
    const int grow = rowOff + blockIdx.x;
    const u16* drow = dots + (size_t)blockIdx.x * VOC;

    for (int i = tid; i < 8192; i += 256) hist[i] = 0;
    for (int i = tid; i < DIM; i += 256) q2s[i] = q2[(size_t)grow * DIM + i];
    if (tid == 0) s_cnt = 0;
    __syncthreads();

    // pass 0: histogram of 13-bit sortable bf16 key
    for (int i = tid; i < VOC; i += 256) {
        u16 u = drow[i];
        u16 key = (u & 0x8000u) ? (u16)~u : (u16)(u | 0x8000u);
        atomicAdd(&hist[key >> 3], 1u);
    }
    __syncthreads();

    // boundary bin: descending cumulative count reaches TOPK; extend 1 bin
    unsigned int segsum = 0;
    for (int b = 0; b < 32; b++) segsum += hist[tid * 32 + b];
    redu[tid] = segsum;
    __syncthreads();
    if (tid == 0) {
        unsigned int cum = 0;
        int seg = 0;
        for (int s = 255; s >= 0; s--) {
            if (cum + redu[s] >= TOPK) { seg = s; break; }
            cum += redu[s];
        }
        unsigned int bbin = (unsigned int)(seg * 32);
        for (int b = seg * 32 + 31; b >= seg * 32; b--) {
            if (cum + hist[b] >= TOPK) { bbin = (unsigned int)b; break; }
            cum += hist[b];
        }
        s_bstart = (bbin > 0) ? bbin - 1 : 0;   // margin: 1 bin >> bf16 error
    }
    __syncthreads();

    // pass 1: collect candidate indices
    const unsigned int bstart = s_bstart;
    for (int i = tid; i < VOC; i += 256) {
        u16 u = drow[i];
        u16 key = (u & 0x8000u) ? (u16)~u : (u16)(u | 0x8000u);
        if ((unsigned int)(key >> 3) >= bstart) {
            unsigned int p = atomicAdd(&s_cnt, 1u);
            if (p < 256) candIdx[p] = i;
        }
    }
    __syncthreads();
    unsigned int cnt = s_cnt;
    if (cnt > 256) cnt = 256;

    // exact fp64 recompute for candidates
    unsigned long long mykey = ~0ULL;
    if (tid < (int)cnt) {
        int idx = candIdx[tid];
        const float* cb = codebook + (size_t)idx * DIM;
        double s = 0.0;
        for (int d = 0; d < DIM; d += 4) {
            float4 c4 = *(const float4*)(cb + d);
            s += (double)q2s[d + 0] * (double)c4.x;
            s += (double)q2s[d + 1] * (double)c4.y;
            s += (double)q2s[d + 2] * (double)c4.z;
            s += (double)q2s[d + 3] * (double)c4.w;
        }
        float val = (float)s;
        unsigned int b = __float_as_uint(val);
        unsigned int skey = (b & 0x80000000u) ? ~b : (b | 0x80000000u);
        mykey = ((unsigned long long)(~skey) << 32) | (unsigned int)idx;
    }
    keys[tid] = mykey;
    __syncthreads();

    // bitonic sort 256 ascending (= descending by exact value)
    for (int k = 2; k <= 256; k <<= 1) {
        for (int j = k >> 1; j > 0; j >>= 1) {
            int ixj = tid ^ j;
            if (ixj > tid) {
                bool up = ((tid & k) == 0);
                unsigned long long a = keys[tid], b2 = keys[ixj];
                if (up ? (a > b2) : (a < b2)) { keys[tid] = b2; keys[ixj] = a; }
            }
            __syncthreads();
        }
    }

    // threshold = exact 64th largest; keep all >= thresh (ties included)
    const unsigned int threshInv = (unsigned int)(keys[TOPK - 1] >> 32);
    const unsigned int topInv    = (unsigned int)(keys[0] >> 32);
    unsigned int tsk = ~topInv;
    float vmax = __uint_as_float((tsk & 0x80000000u) ? (tsk & 0x7FFFFFFFu) : ~tsk);

    unsigned int hi = (unsigned int)(keys[tid] >> 32);
    bool sel = (hi <= threshInv);
    unsigned int skey = ~hi;
    float val = __uint_as_float((skey & 0x80000000u) ? (skey & 0x7FFFFFFFu) : ~skey);
    float w = sel ? expf(val - vmax) : 0.f;
    wArr[tid] = w;
    redf[tid] = w;
    redu[tid] = sel ? 1u : 0u;
    __syncthreads();
    for (int s = 128; s > 0; s >>= 1) {
        if (tid < s) { redf[tid] += redf[tid + s]; redu[tid] += redu[tid + s]; }
        __syncthreads();
    }
    const float invZ = 1.0f / redf[0];
    const int selCount = (int)redu[0];        // sorted => selected is a prefix

    for (int d = tid; d < DIM; d += 256) {
        float acc = 0.f;
        for (int i = 0; i < selCount; i++) {
            unsigned int idx = (unsigned int)(keys[i] & 0xFFFFFFFFu);
            acc += wArr[i] * v[(size_t)idx * DIM + d];
        }
        out[(size_t)grow * DIM + d] = acc * invZ;
    }
}

// ---------------------------------------------------------------------------
extern "C" void kernel_launch(void* const* d_in, const int* in_sizes, int n_in,
                              void* d_out, int out_size, void* d_ws, size_t ws_size,
                              hipStream_t stream)
{
    const float* x        = (const float*)d_in[0];
    const float* codebook = (const float*)d_in[1];
    const float* Wq       = (const float*)d_in[2];
    const float* bq       = (const float*)d_in[3];
    const float* Wk       = (const float*)d_in[4];
    // d_in[5] = bk: per-row-constant shift in dots (invariant under top-k and
    // softmax) — intentionally unused.
    const float* Wv       = (const float*)d_in[6];
    const float* bv       = (const float*)d_in[7];
    float* out = (float*)d_out;

    // workspace layout — base = 142 MB; dots chunk sized from what remains.
    float* q2  = (float*)d_ws;                        // 4096x512      (8 MB)
    float* Wqk = q2  + (size_t)BATCH * DIM;           // 512x512       (1 MB)
    float* bqk = Wqk + (size_t)DIM * DIM;             // 512 (pad 1024)
    float* v   = bqk + 1024;                          // 32768x512    (64 MB)
    u16* q2h = (u16*)(v + (size_t)VOC * DIM);         // 4 MB
    u16* cbh = q2h + (size_t)BATCH * DIM;             // 32 MB
    u16* cbl = cbh + (size_t)VOC * DIM;               // 32 MB
    u16* wvh = cbl + (size_t)VOC * DIM;               // 0.5 MB
    u16* wvl = wvh + (size_t)DIM * DIM;               // 0.5 MB
    u16* dots = wvl + (size_t)DIM * DIM;              // chunk x 32768 bf16

    const size_t base = ((size_t)BATCH * DIM * 2 + (size_t)DIM * DIM + 1024
                         + (size_t)VOC * DIM) * sizeof(float)
                      + ((size_t)BATCH * DIM + 2 * (size_t)VOC * DIM
                         + 2 * (size_t)DIM * DIM) * sizeof(u16);
    size_t rem = (ws_size > base) ? (ws_size - base) : 0;
    int chunk = (int)(rem / ((size_t)VOC * sizeof(u16)));
    if (chunk > BATCH) chunk = BATCH;
    chunk = (chunk / 128) * 128;
    if (chunk < 128) chunk = 128;

    dim3 blk(256);

    // Wqk = Wq @ Wk^T (fp32 + f64 tile-flush)
    gemm_kernel<true, true><<<dim3(DIM / 64, DIM / 128), blk, 0, stream>>>(
        Wq, Wk, nullptr, Wqk, DIM, DIM, DIM);
    // bqk = bq @ Wk^T
    bias_fold<<<dim3(2), blk, 0, stream>>>(bq, Wk, bqk);
    // q2 = x @ Wqk + bqk  (fp32 + f64 tile-flush: selection-critical)
    gemm_kernel<false, true><<<dim3(DIM / 64, BATCH / 128), blk, 0, stream>>>(
        x, Wqk, bqk, q2, BATCH, DIM, DIM);

    // pack operands into MFMA fragment layout
    pack_rows<<<dim3(BATCH * 64 / 256), blk, 0, stream>>>(q2, q2h, nullptr, BATCH, 12);
    pack_rows<<<dim3(VOC * 64 / 256), blk, 0, stream>>>(codebook, cbh, cbl, VOC, 15);
    pack_bT<<<dim3(DIM * 64 / 256), blk, 0, stream>>>(Wv, wvh, wvl);

    // v = codebook @ Wv + bv   (bf16 hi/lo split, 3 MFMA passes, fp32 out)
    mfma_gemm<3, false><<<dim3(DIM / 128, VOC / 128), blk, 0, stream>>>(
        cbh, cbl, wvh, wvl, bv, v, 0, VOC, DIM);

    // dots (chunked) = q2 @ codebook^T  (bf16 1-pass, bf16 out — candidates)
    for (int r0 = 0; r0 < BATCH; r0 += chunk) {
        int rows = BATCH - r0;
        if (rows > chunk) rows = chunk;
        mfma_gemm<1, true><<<dim3(VOC / 128, rows / 128), blk, 0, stream>>>(
            q2h, nullptr, cbh, nullptr, nullptr, dots, r0, BATCH, VOC);
        select2<<<dim3(rows), blk, 0, stream>>>(dots, q2, codebook, v, out, r0);
    }
}

// Round 4
// 902.870 us; speedup vs baseline: 3.0998x; 1.6349x over previous
//
#include <hip/hip_runtime.h>
#include <cstdint>

#define VOC   32768
#define DIM   512
#define TOPK  64
#define BATCH 4096

typedef unsigned short u16;
typedef __attribute__((ext_vector_type(8))) short bf16x8;
typedef __attribute__((ext_vector_type(4))) float f32x4;

// ---- bf16 helpers (RNE) ----------------------------------------------------
__device__ __forceinline__ u16 f2bf(float f) {
    unsigned u = __float_as_uint(f);
    unsigned r = (u + 0x7FFFu + ((u >> 16) & 1u)) >> 16;
    return (u16)r;
}
__device__ __forceinline__ float bf2f(u16 h) {
    unsigned u = ((unsigned)h) << 16;
    return __uint_as_float(u);
}

// ---- async global->LDS 16B -------------------------------------------------
__device__ __forceinline__ void async16(const void* g, void* l) {
    __builtin_amdgcn_global_load_lds(
        (const __attribute__((address_space(1))) void*)g,
        (__attribute__((address_space(3))) void*)l, 16, 0, 0);
}

// ---------------------------------------------------------------------------
// fp32 tiled GEMM + optional per-k-tile fp64 flush (round-1, known good).
//   BT=false: C = A(MxK) * B(KxN) (+bias) ;  BT=true: C = A * B^T, B is NxK
// ---------------------------------------------------------------------------
template <bool BT, bool F64ACC>
__global__ __launch_bounds__(256)
void gemm_kernel(const float* __restrict__ A, const float* __restrict__ B,
                 const float* __restrict__ bias, float* __restrict__ C,
                 int M, int N, int K)
{
    const int BM = 128, BN = 64, KS = 16;
    __shared__ float As[KS][BM + 4];
    __shared__ float Bs[KS][BN];

    const int tid = threadIdx.x;
    const int m0 = blockIdx.y * BM;
    const int n0 = blockIdx.x * BN;
    const int ty = tid >> 4;
    const int tx = tid & 15;

    float acc[8][4];
    double acc64[8][4];
#pragma unroll
    for (int i = 0; i < 8; i++)
#pragma unroll
        for (int j = 0; j < 4; j++) { acc[i][j] = 0.f; if (F64ACC) acc64[i][j] = 0.0; }

    for (int kt = 0; kt < K; kt += KS) {
#pragma unroll
        for (int s = 0; s < 2; s++) {
            int c = tid + s * 256;
            int row = c >> 2;
            int kq  = c & 3;
            const float4 av = *(const float4*)(A + (size_t)(m0 + row) * K + kt + kq * 4);
            As[kq * 4 + 0][row] = av.x;
            As[kq * 4 + 1][row] = av.y;
            As[kq * 4 + 2][row] = av.z;
            As[kq * 4 + 3][row] = av.w;
        }
        if (!BT) {
            int krow = tid >> 4;
            int nq   = tid & 15;
            const float4 bv = *(const float4*)(B + (size_t)(kt + krow) * N + n0 + nq * 4);
            *(float4*)&Bs[krow][nq * 4] = bv;
        } else {
            int nrow = tid >> 2;
            int kq   = tid & 3;
            const float4 bv = *(const float4*)(B + (size_t)(n0 + nrow) * K + kt + kq * 4);
            Bs[kq * 4 + 0][nrow] = bv.x;
            Bs[kq * 4 + 1][nrow] = bv.y;
            Bs[kq * 4 + 2][nrow] = bv.z;
            Bs[kq * 4 + 3][nrow] = bv.w;
        }
        __syncthreads();

#pragma unroll
        for (int kk = 0; kk < KS; kk++) {
            float4 a0 = *(const float4*)&As[kk][ty * 8];
            float4 a1 = *(const float4*)&As[kk][ty * 8 + 4];
            float4 b  = *(const float4*)&Bs[kk][tx * 4];
            float av[8] = {a0.x, a0.y, a0.z, a0.w, a1.x, a1.y, a1.z, a1.w};
            float bv[4] = {b.x, b.y, b.z, b.w};
#pragma unroll
            for (int i = 0; i < 8; i++)
#pragma unroll
                for (int j = 0; j < 4; j++)
                    acc[i][j] += av[i] * bv[j];
        }
        __syncthreads();
        if (F64ACC) {
#pragma unroll
            for (int i = 0; i < 8; i++)
#pragma unroll
                for (int j = 0; j < 4; j++) { acc64[i][j] += (double)acc[i][j]; acc[i][j] = 0.f; }
        }
    }

    float4 bb = make_float4(0.f, 0.f, 0.f, 0.f);
    if (bias) bb = *(const float4*)(bias + n0 + tx * 4);
#pragma unroll
    for (int i = 0; i < 8; i++) {
        float4 o;
        float r0 = F64ACC ? (float)acc64[i][0] : acc[i][0];
        float r1 = F64ACC ? (float)acc64[i][1] : acc[i][1];
        float r2 = F64ACC ? (float)acc64[i][2] : acc[i][2];
        float r3 = F64ACC ? (float)acc64[i][3] : acc[i][3];
        o.x = r0 + bb.x; o.y = r1 + bb.y; o.z = r2 + bb.z; o.w = r3 + bb.w;
        *(float4*)(C + (size_t)(m0 + ty * 8 + i) * N + n0 + tx * 4) = o;
    }
}

// ---------------------------------------------------------------------------
__global__ void bias_fold(const float* __restrict__ bq, const float* __restrict__ Wk,
                          float* __restrict__ bqk)
{
    int j = blockIdx.x * 256 + threadIdx.x;
    if (j >= DIM) return;
    double s = 0.0;
    const float* wr = Wk + (size_t)j * DIM;
    for (int d = 0; d < DIM; d++) s += (double)bq[d] * (double)wr[d];
    bqk[j] = (float)s;
}

// ---------------------------------------------------------------------------
// Pack fp32 [R x 512] -> MFMA operand layout pk[ks][ch][R][8] bf16 (+lo).
// ---------------------------------------------------------------------------
__global__ __launch_bounds__(256)
void pack_rows(const float* __restrict__ src, u16* __restrict__ hi,
               u16* __restrict__ lo, int R, int log2R)
{
    int idx = blockIdx.x * 256 + threadIdx.x;      // R*64 total
    int c8  = idx >> log2R;
    int row = idx & (R - 1);
    const float* sp = src + (size_t)row * DIM + c8 * 8;
    float xv[8];
    *(float4*)&xv[0] = *(const float4*)sp;
    *(float4*)&xv[4] = *(const float4*)(sp + 4);
    int ks = c8 >> 2, ch = c8 & 3;
    size_t ob = ((size_t)(ks * 4 + ch) * R + row) * 8;
    u16 h[8], l[8];
#pragma unroll
    for (int j = 0; j < 8; j++) {
        h[j] = f2bf(xv[j]);
        l[j] = f2bf(xv[j] - bf2f(h[j]));
    }
    *(uint4*)(hi + ob) = *(const uint4*)h;
    if (lo) *(uint4*)(lo + ob) = *(const uint4*)l;
}

// ---------------------------------------------------------------------------
// Pack Wv (512x512, B-operand: B[k][n]) -> pk[ks][ch][512(n)][8(k)]
// ---------------------------------------------------------------------------
__global__ __launch_bounds__(256)
void pack_bT(const float* __restrict__ W, u16* __restrict__ hi, u16* __restrict__ lo)
{
    int idx = blockIdx.x * 256 + threadIdx.x;      // 512*64 total
    int n  = idx & (DIM - 1);
    int c8 = idx >> 9;
    int ks = c8 >> 2, ch = c8 & 3;
    size_t ob = ((size_t)(ks * 4 + ch) * DIM + n) * 8;
    u16 h[8], l[8];
#pragma unroll
    for (int j = 0; j < 8; j++) {
        float x = W[(size_t)(c8 * 8 + j) * DIM + n];
        h[j] = f2bf(x);
        l[j] = f2bf(x - bf2f(h[j]));
    }
    *(uint4*)(hi + ob) = *(const uint4*)h;
    if (lo) *(uint4*)(lo + ob) = *(const uint4*)l;
}

// ---------------------------------------------------------------------------
// MFMA GEMM (round-3, known good): C[m][n] = sum_k A[mBase+m][k]*B[n][k].
// ---------------------------------------------------------------------------
template <int NPROD, bool OUT_BF16>
__global__ __launch_bounds__(256, 2)
void mfma_gemm(const u16* __restrict__ Ah, const u16* __restrict__ Al,
               const u16* __restrict__ Bh, const u16* __restrict__ Bl,
               const float* __restrict__ bias, void* __restrict__ Cout,
               int mBase, int Mpack, int N)
{
    constexpr int NARR = (NPROD == 3) ? 4 : 2;
    __shared__ u16 lds[NARR * 4096];

    const int tid  = threadIdx.x;
    const int lane = tid & 63;
    const int wave = tid >> 6;
    const int wm = wave >> 1, wn = wave & 1;
    const int m0 = blockIdx.y * 128, n0 = blockIdx.x * 128;
    const int lr = lane & 15;
    const int q  = lane >> 4;

    f32x4 acc[4][4] = {};
    const u16* garr[4] = {Ah, Bh, Al, Bl};

    for (int ks = 0; ks < 16; ks++) {
        if (NPROD == 3) {
            const int a = wave;
            const u16* src = garr[a];
            const bool isA = (a == 0 || a == 2);
            const int rb = isA ? (mBase + m0) : n0;
            const int R  = isA ? Mpack : N;
#pragma unroll
            for (int i = 0; i < 8; i++) {
                const u16* gp = src + ((size_t)(ks * 4 + (i >> 1)) * R + rb + (i & 1) * 64 + lane) * 8;
                u16* lp = &lds[a * 4096 + i * 512 + lane * 8];
                async16(gp, lp);
            }
        } else {
            const int a = wave >> 1;
            const u16* src = garr[a];
            const bool isA = (a == 0);
            const int rb = isA ? (mBase + m0) : n0;
            const int R  = isA ? Mpack : N;
#pragma unroll
            for (int s = 0; s < 4; s++) {
                int i = (wave & 1) * 4 + s;
                const u16* gp = src + ((size_t)(ks * 4 + (i >> 1)) * R + rb + (i & 1) * 64 + lane) * 8;
                u16* lp = &lds[a * 4096 + i * 512 + lane * 8];
                async16(gp, lp);
            }
        }
        __syncthreads();

        bf16x8 ah[4], al[4];
#pragma unroll
        for (int mt = 0; mt < 4; mt++) {
            int row = wm * 64 + mt * 16 + lr;
            ah[mt] = *(const bf16x8*)&lds[0 * 4096 + q * 1024 + row * 8];
            if (NPROD == 3) al[mt] = *(const bf16x8*)&lds[2 * 4096 + q * 1024 + row * 8];
        }
#pragma unroll
        for (int nt = 0; nt < 4; nt++) {
            int col = wn * 64 + nt * 16 + lr;
            bf16x8 bh = *(const bf16x8*)&lds[1 * 4096 + q * 1024 + col * 8];
            bf16x8 bl;
            if (NPROD == 3) bl = *(const bf16x8*)&lds[3 * 4096 + q * 1024 + col * 8];
#pragma unroll
            for (int mt = 0; mt < 4; mt++) {
                acc[mt][nt] = __builtin_amdgcn_mfma_f32_16x16x32_bf16(ah[mt], bh, acc[mt][nt], 0, 0, 0);
                if (NPROD == 3) {
                    acc[mt][nt] = __builtin_amdgcn_mfma_f32_16x16x32_bf16(ah[mt], bl, acc[mt][nt], 0, 0, 0);
                    acc[mt][nt] = __builtin_amdgcn_mfma_f32_16x16x32_bf16(al[mt], bh, acc[mt][nt], 0, 0, 0);
                }
            }
        }
        __syncthreads();
    }

#pragma unroll
    for (int mt = 0; mt < 4; mt++) {
#pragma unroll
        for (int nt = 0; nt < 4; nt++) {
            int col = n0 + wn * 64 + nt * 16 + lr;
            float bb = bias ? bias[col] : 0.f;
#pragma unroll
            for (int r = 0; r < 4; r++) {
                int rowg = m0 + wm * 64 + mt * 16 + q * 4 + r;   // chunk-local
                float val = acc[mt][nt][r] + bb;
                if (OUT_BF16)
                    ((u16*)Cout)[(size_t)rowg * N + col] = f2bf(val);
                else
                    ((float*)Cout)[(size_t)rowg * N + col] = val;
            }
        }
    }
}

// ---------------------------------------------------------------------------
// Select v3: stats-threshold candidate nomination (no histogram, no LDS
// atomics on hot path), vectorized uint4 dots reads, exact fp64 rescue,
// verified-threshold retry loop (proves no true top-64 element was missed:
// any missed e has exact(e) >= v64 >= w64, so approx(e) >= w64-EPS >= t).
// ---------------------------------------------------------------------------
#define CAND_CAP 256
#define SEL_EPS  0.015f

__global__ __launch_bounds__(256)
void select3(const u16* __restrict__ dots, const float* __restrict__ q2,
             const float* __restrict__ codebook, const float* __restrict__ v,
             float* __restrict__ out, int rowOff)
{
    __shared__ float q2s[DIM];
    __shared__ unsigned long long keys[CAND_CAP];
    __shared__ int candIdx[CAND_CAP];
    __shared__ float wArr[CAND_CAP];
    __shared__ float redf[256];
    __shared__ unsigned int redu[256];
    __shared__ float redA[4], redB[4], redC[4];
    __shared__ unsigned int s_cnt;

    const int tid  = threadIdx.x;
    const int lane = tid & 63;
    const int wave = tid >> 6;
    const int grow = rowOff + blockIdx.x;
    const u16* drow = dots + (size_t)blockIdx.x * VOC;

    for (int i = tid; i < DIM; i += 256) q2s[i] = q2[(size_t)grow * DIM + i];

    // ---- pass A: vectorized stats (sum, sumsq, max) ----
    float sum = 0.f, sumsq = 0.f, vmx = -3.4e38f;
    for (int base = tid * 8; base < VOC; base += 2048) {
        uint4 pk = *(const uint4*)(drow + base);
        unsigned wd[4] = {pk.x, pk.y, pk.z, pk.w};
#pragma unroll
        for (int j = 0; j < 4; j++) {
            float lo = __uint_as_float(wd[j] << 16);
            float hi = __uint_as_float(wd[j] & 0xFFFF0000u);
            sum += lo + hi;
            sumsq += lo * lo + hi * hi;
            vmx = fmaxf(vmx, fmaxf(lo, hi));
        }
    }
#pragma unroll
    for (int off = 32; off > 0; off >>= 1) {
        sum   += __shfl_down(sum, off, 64);
        sumsq += __shfl_down(sumsq, off, 64);
        vmx    = fmaxf(vmx, __shfl_down(vmx, off, 64));
    }
    if (lane == 0) { redA[wave] = sum; redB[wave] = sumsq; redC[wave] = vmx; }
    __syncthreads();
    const float fsum = redA[0] + redA[1] + redA[2] + redA[3];
    const float fss  = redB[0] + redB[1] + redB[2] + redB[3];
    const float rmax = fmaxf(fmaxf(redC[0], redC[1]), fmaxf(redC[2], redC[3]));
    const float mu  = fsum * (1.f / VOC);
    const float sig = sqrtf(fmaxf(fss * (1.f / VOC) - mu * mu, 1e-12f));

    // ---- pass B: collect approx >= t; exact rescue; verify; retry ----
    float t = fminf(mu + 2.6f * sig, rmax);   // E[cnt] ~ 153
    unsigned int cnt = 0;
    float vmax64 = 0.f;

    for (int it = 0; it < 12; it++) {
        if (tid == 0) s_cnt = 0;
        __syncthreads();
        for (int base = tid * 8; base < VOC; base += 2048) {
            uint4 pk = *(const uint4*)(drow + base);
            unsigned wd[4] = {pk.x, pk.y, pk.z, pk.w};
#pragma unroll
            for (int j = 0; j < 4; j++) {
                float lo = __uint_as_float(wd[j] << 16);
                float hi = __uint_as_float(wd[j] & 0xFFFF0000u);
                if (lo >= t) {
                    unsigned p = atomicAdd(&s_cnt, 1u);
                    if (p < CAND_CAP) candIdx[p] = base + 2 * j;
                }
                if (hi >= t) {
                    unsigned p = atomicAdd(&s_cnt, 1u);
                    if (p < CAND_CAP) candIdx[p] = base + 2 * j + 1;
                }
            }
        }
        __syncthreads();
        unsigned int total = s_cnt;
        if (total < TOPK)      { t -= 0.35f * sig; __syncthreads(); continue; }
        if (total > CAND_CAP)  { t += 0.25f * sig; __syncthreads(); continue; }
        cnt = total;

        // exact fp64 recompute for candidates
        unsigned long long mykey = ~0ULL;
        if (tid < (int)cnt) {
            int idx = candIdx[tid];
            const float* cb = codebook + (size_t)idx * DIM;
            double s = 0.0;
            for (int d = 0; d < DIM; d += 4) {
                float4 c4 = *(const float4*)(cb + d);
                s += (double)q2s[d + 0] * (double)c4.x;
                s += (double)q2s[d + 1] * (double)c4.y;
                s += (double)q2s[d + 2] * (double)c4.z;
                s += (double)q2s[d + 3] * (double)c4.w;
            }
            float val = (float)s;
            unsigned int b = __float_as_uint(val);
            unsigned int skey = (b & 0x80000000u) ? ~b : (b | 0x80000000u);
            mykey = ((unsigned long long)(~skey) << 32) | (unsigned int)idx;
        }
        keys[tid] = mykey;
        __syncthreads();

        // bitonic sort 256 ascending (= descending by exact value)
        for (int k = 2; k <= 256; k <<= 1) {
            for (int j = k >> 1; j > 0; j >>= 1) {
                int ixj = tid ^ j;
                if (ixj > tid) {
                    bool up = ((tid & k) == 0);
                    unsigned long long a = keys[tid], b2 = keys[ixj];
                    if (up ? (a > b2) : (a < b2)) { keys[tid] = b2; keys[ixj] = a; }
                }
                __syncthreads();
            }
        }

        // w64 = exact 64th largest among candidates; verify margin
        unsigned int h64 = (unsigned int)(keys[TOPK - 1] >> 32);
        unsigned int sk64 = ~h64;
        float w64 = __uint_as_float((sk64 & 0x80000000u) ? (sk64 & 0x7FFFFFFFu) : ~sk64);
        unsigned int h0 = (unsigned int)(keys[0] >> 32);
        unsigned int sk0 = ~h0;
        vmax64 = __uint_as_float((sk0 & 0x80000000u) ? (sk0 & 0x7FFFFFFFu) : ~sk0);

        if (t <= w64 - SEL_EPS) break;        // proven: candidate set covers top-64
        t = w64 - 1.5f * SEL_EPS;             // widen and redo
        __syncthreads();
    }

    // ---- threshold = exact 64th; keep all >= thresh (ties); softmax ----
    const unsigned int threshInv = (unsigned int)(keys[TOPK - 1] >> 32);
    unsigned int hi = (unsigned int)(keys[tid] >> 32);
    bool sel = (hi <= threshInv);
    unsigned int skey = ~hi;
    float val = __uint_as_float((skey & 0x80000000u) ? (skey & 0x7FFFFFFFu) : ~skey);
    float w = sel ? expf(val - vmax64) : 0.f;
    wArr[tid] = w;
    redf[tid] = w;
    redu[tid] = sel ? 1u : 0u;
    __syncthreads();
    for (int s = 128; s > 0; s >>= 1) {
        if (tid < s) { redf[tid] += redf[tid + s]; redu[tid] += redu[tid + s]; }
        __syncthreads();
    }
    const float invZ = 1.0f / redf[0];
    const int selCount = (int)redu[0];        // sorted => selected is a prefix

    for (int d = tid; d < DIM; d += 256) {
        float acc = 0.f;
        for (int i = 0; i < selCount; i++) {
            unsigned int idx = (unsigned int)(keys[i] & 0xFFFFFFFFu);
            acc += wArr[i] * v[(size_t)idx * DIM + d];
        }
        out[(size_t)grow * DIM + d] = acc * invZ;
    }
}

// ---------------------------------------------------------------------------
extern "C" void kernel_launch(void* const* d_in, const int* in_sizes, int n_in,
                              void* d_out, int out_size, void* d_ws, size_t ws_size,
                              hipStream_t stream)
{
    const float* x        = (const float*)d_in[0];
    const float* codebook = (const float*)d_in[1];
    const float* Wq       = (const float*)d_in[2];
    const float* bq       = (const float*)d_in[3];
    const float* Wk       = (const float*)d_in[4];
    // d_in[5] = bk: per-row-constant shift in dots (invariant under top-k and
    // softmax) — intentionally unused.
    const float* Wv       = (const float*)d_in[6];
    const float* bv       = (const float*)d_in[7];
    float* out = (float*)d_out;

    // workspace layout — base = 142 MB; dots chunk sized from what remains.
    float* q2  = (float*)d_ws;                        // 4096x512      (8 MB)
    float* Wqk = q2  + (size_t)BATCH * DIM;           // 512x512       (1 MB)
    float* bqk = Wqk + (size_t)DIM * DIM;             // 512 (pad 1024)
    float* v   = bqk + 1024;                          // 32768x512    (64 MB)
    u16* q2h = (u16*)(v + (size_t)VOC * DIM);         // 4 MB
    u16* cbh = q2h + (size_t)BATCH * DIM;             // 32 MB
    u16* cbl = cbh + (size_t)VOC * DIM;               // 32 MB
    u16* wvh = cbl + (size_t)VOC * DIM;               // 0.5 MB
    u16* wvl = wvh + (size_t)DIM * DIM;               // 0.5 MB
    u16* dots = wvl + (size_t)DIM * DIM;              // chunk x 32768 bf16

    const size_t base = ((size_t)BATCH * DIM * 2 + (size_t)DIM * DIM + 1024
                         + (size_t)VOC * DIM) * sizeof(float)
                      + ((size_t)BATCH * DIM + 2 * (size_t)VOC * DIM
                         + 2 * (size_t)DIM * DIM) * sizeof(u16);
    size_t rem = (ws_size > base) ? (ws_size - base) : 0;
    int chunk = (int)(rem / ((size_t)VOC * sizeof(u16)));
    if (chunk > 1024) chunk = 1024;   // keep {dots,codebook,v} L3-resident
    chunk = (chunk / 128) * 128;
    if (chunk < 128) chunk = 128;

    dim3 blk(256);

    // Wqk = Wq @ Wk^T (fp32 + f64 tile-flush)
    gemm_kernel<true, true><<<dim3(DIM / 64, DIM / 128), blk, 0, stream>>>(
        Wq, Wk, nullptr, Wqk, DIM, DIM, DIM);
    // bqk = bq @ Wk^T
    bias_fold<<<dim3(2), blk, 0, stream>>>(bq, Wk, bqk);
    // q2 = x @ Wqk + bqk  (fp32 + f64 tile-flush: selection-critical)
    gemm_kernel<false, true><<<dim3(DIM / 64, BATCH / 128), blk, 0, stream>>>(
        x, Wqk, bqk, q2, BATCH, DIM, DIM);

    // pack operands into MFMA fragment layout
    pack_rows<<<dim3(BATCH * 64 / 256), blk, 0, stream>>>(q2, q2h, nullptr, BATCH, 12);
    pack_rows<<<dim3(VOC * 64 / 256), blk, 0, stream>>>(codebook, cbh, cbl, VOC, 15);
    pack_bT<<<dim3(DIM * 64 / 256), blk, 0, stream>>>(Wv, wvh, wvl);

    // v = codebook @ Wv + bv   (bf16 hi/lo split, 3 MFMA passes, fp32 out)
    mfma_gemm<3, false><<<dim3(DIM / 128, VOC / 128), blk, 0, stream>>>(
        cbh, cbl, wvh, wvl, bv, v, 0, VOC, DIM);

    // dots (chunked) = q2 @ codebook^T  (bf16 1-pass, bf16 out — candidates)
    for (int r0 = 0; r0 < BATCH; r0 += chunk) {
        int rows = BATCH - r0;
        if (rows > chunk) rows = chunk;
        mfma_gemm<1, true><<<dim3(VOC / 128, rows / 128), blk, 0, stream>>>(
            q2h, nullptr, cbh, nullptr, nullptr, dots, r0, BATCH, VOC);
        select3<<<dim3(rows), blk, 0, stream>>>(dots, q2, codebook, v, out, r0);
    }
}